// Round 7
// baseline (177.239 us; speedup 1.0000x reference)
//
#include <hip/hip_runtime.h>

#define NN 100000
#define SS 50000
#define KK 32
#define CC 128
#define RPB 80           // rows per proj block; 1250 * 80 = 100000
                         // (R7: halved from 160 -- 625 blocks = 2.44/CU had a
                         // ~20% grid-quantization tail; 1250 = 4.88/CU ~2%)
#define LDA 136          // LDS row stride in halfs (272 B = 17*16, b128-aligned)
#define PTHR 1e-8f       // agg fetch filter: p_raw below this contributes
                         // <= 32*1e-8*|v|max ~ 5e-6 after normalization

typedef _Float16 f16x8 __attribute__((ext_vector_type(8)));
typedef _Float16 f16x4 __attribute__((ext_vector_type(4)));
typedef _Float16 f16x2 __attribute__((ext_vector_type(2)));
typedef float f32x4 __attribute__((ext_vector_type(4)));

// Single-instruction lane exchange for xor-masks < 32: ds_swizzle BitMode,
// offset = (xor_mask<<10) | (or<<5) | and_mask. Replaces HIP __shfl_xor's
// v_xor+v_lshl+ds_bpermute (2 VALU + 1 DS) with 1 DS op, no addr chain.
template<int PAT>
__device__ __forceinline__ float swz(float x) {
    return __int_as_float(__builtin_amdgcn_ds_swizzle(__float_as_int(x), PAT));
}
#define SWZ_X1  0x041F
#define SWZ_X2  0x081F
#define SWZ_X4  0x101F
#define SWZ_X8  0x201F
#define SWZ_X16 0x401F

// Workspace table T: per row i (512 B stride, 256 halfs):
//   T[i*256 +   0 .. 127] = fp16(word_vec[i])   (proj staging loop)
//   T[i*256 + 128 .. 255] = fp16(P[i])          (proj epilogue)

// ---------------------------------------------------------------------------
// Kernel 1 (fused convert+proj): P = leaky_relu(wv @ W^T + b) via
// mfma_f32_16x16x32_f16. 80 rows/block staged once into LDS (fp16, padded)
// with coalesced float4 loads; same loop publishes the fp16 wv copy to T.
// A-frags from LDS (broadcast); B-frags register-resident per wave.
// ---------------------------------------------------------------------------
__global__ __launch_bounds__(256) void proj_kernel(
    const float* __restrict__ wv,
    const float* __restrict__ W,
    const float* __restrict__ bias,
    _Float16* __restrict__ T,
    float* __restrict__ out)
{
    __shared__ _Float16 sA[RPB][LDA];

    const int t = threadIdx.x;
    const int base = blockIdx.x * RPB;

    // Stage A (80 x 128 fp32 -> fp16 LDS + T copy). 10 float4 per thread.
    #pragma unroll 5
    for (int i = 0; i < 10; i++) {
        const int idx = i * 256 + t;
        const int row = idx >> 5;
        const int c4 = (idx & 31) * 4;
        const float4 v = *(const float4*)(wv + (size_t)(base + row) * CC + c4);
        f16x4 h;
        h[0] = (_Float16)v.x; h[1] = (_Float16)v.y;
        h[2] = (_Float16)v.z; h[3] = (_Float16)v.w;
        *(f16x4*)&sA[row][c4] = h;
        *(f16x4*)(T + (size_t)(base + row) * 256 + c4) = h;
    }

    const int w = t >> 6;
    const int l = t & 63;
    const int q = l >> 4;      // quad 0..3
    const int c = l & 15;

    // B-frags: B[k][n] = W[n][k]; lane holds n = w*32+nch*16+c, k = kc*32+q*8+j
    f16x8 bf[2][4];
    float bo[2];
    #pragma unroll
    for (int nch = 0; nch < 2; nch++) {
        const int n = w * 32 + nch * 16 + c;
        bo[nch] = bias[n];
        const float* Wr = W + (size_t)n * CC;
        #pragma unroll
        for (int kc = 0; kc < 4; kc++) {
            const int k0 = kc * 32 + q * 8;
            const float4 w0 = *(const float4*)(Wr + k0);
            const float4 w1 = *(const float4*)(Wr + k0 + 4);
            f16x8 b;
            b[0] = (_Float16)w0.x; b[1] = (_Float16)w0.y;
            b[2] = (_Float16)w0.z; b[3] = (_Float16)w0.w;
            b[4] = (_Float16)w1.x; b[5] = (_Float16)w1.y;
            b[6] = (_Float16)w1.z; b[7] = (_Float16)w1.w;
            bf[nch][kc] = b;
        }
    }
    __syncthreads();

    #pragma unroll 2
    for (int sub = 0; sub < RPB / 16; sub++) {
        const int rl = sub * 16 + c;

        f16x8 af[4];
        #pragma unroll
        for (int kc = 0; kc < 4; kc++)
            af[kc] = *(const f16x8*)&sA[rl][kc * 32 + q * 8];

        f32x4 acc[2] = {{0.f, 0.f, 0.f, 0.f}, {0.f, 0.f, 0.f, 0.f}};
        #pragma unroll
        for (int kc = 0; kc < 4; kc++) {
            acc[0] = __builtin_amdgcn_mfma_f32_16x16x32_f16(af[kc], bf[0][kc], acc[0], 0, 0, 0);
            acc[1] = __builtin_amdgcn_mfma_f32_16x16x32_f16(af[kc], bf[1][kc], acc[1], 0, 0, 0);
        }

        // D layout: col = c (+tile offset), row = q*4 + reg.
        #pragma unroll
        for (int nch = 0; nch < 2; nch++) {
            const int col = w * 32 + nch * 16 + c;
            #pragma unroll
            for (int r = 0; r < 4; r++) {
                const int row = base + sub * 16 + q * 4 + r;
                float v = acc[nch][r] + bo[nch];
                v = v > 0.f ? v : 0.2f * v;
                out[(size_t)row * CC + col] = v;
                T[(size_t)row * 256 + 128 + col] = (_Float16)v;
            }
        }
    }
}

// ---------------------------------------------------------------------------
// Kernel 2: one wave per s, lane = r*16+c. R6 structure kept (p-based vv
// fetch filter at PTHR=1e-8, vv issue under the softmax tail, grouped gather
// issue, batched index prologue). R7: every lane exchange with xor-mask < 32
// (score reduce x32, max/sum xor16, agg butterfly xor16 x8 -- 42/lane) now
// uses single-instruction ds_swizzle instead of __shfl_xor's
// v_xor+v_lshl+ds_bpermute. Removes ~84 VALU instr/lane from a kernel that
// is issue-bound (VALUBusy 75% at only 2.8 TB/s fetch). Arithmetic is
// bit-identical; only the lane-exchange instruction changes.
// ---------------------------------------------------------------------------
__global__ __launch_bounds__(256, 8) void attn_kernel(
    const _Float16* __restrict__ T,
    const int* __restrict__ src_idx,
    const int* __restrict__ neighs,
    const int* __restrict__ mask,
    float* __restrict__ out)
{
    const int s = (blockIdx.x * 256 + threadIdx.x) >> 6;
    if (s >= SS) return;
    const int lane = threadIdx.x & 63;
    const int c = lane & 15;
    const int r = lane >> 4;

    // Batched index load: lane l (and l+32) holds element l&31 of the row.
    const int e = lane & 31;
    const int nb_l = neighs[s * KK + e];
    const int mk_l = mask[s * KK + e];
    const int src = src_idx[s];

    const unsigned long long mb = __ballot(mk_l == 1);   // bit l = mask[l&31]

    int nbv[8], mbits = 0;
    #pragma unroll
    for (int ch = 0; ch < 8; ch++) {
        nbv[ch] = __shfl(nb_l, ch * 4 + r);
        mbits |= (int)((mb >> (ch * 4 + r)) & 1ull) << ch;
    }

    const char* Tb = (const char*)T;
    const unsigned cb = (unsigned)c << 4;
    const unsigned qoff = ((unsigned)src << 9) + cb;   // q line: L1-hot anchor

    // Phase 1: score gathers, grouped issue. Masked rows -> q line (no new
    // cache lines; values arithmetically discarded).
    const f16x8 qh = *(const f16x8*)(Tb + qoff);
    f16x8 kh[8];
    #pragma unroll
    for (int ch = 0; ch < 8; ch++) {
        const unsigned o = ((mbits >> ch) & 1) ? (((unsigned)nbv[ch] << 9) + cb)
                                               : qoff;
        kh[ch] = *(const f16x8*)(Tb + o);
    }
    __builtin_amdgcn_sched_barrier(0);   // all 8 kh airborne before the dots

    float sc[8];
    #pragma unroll
    for (int ch = 0; ch < 8; ch++) {
        float d = 0.f;
        #pragma unroll
        for (int j = 0; j < 4; j++) {
            f16x2 qa; qa[0] = qh[2 * j];     qa[1] = qh[2 * j + 1];
            f16x2 ka; ka[0] = kh[ch][2 * j]; ka[1] = kh[ch][2 * j + 1];
            d = __builtin_amdgcn_fdot2(qa, ka, d, false);
        }
        d += swz<SWZ_X1>(d);
        d += swz<SWZ_X2>(d);
        d += swz<SWZ_X4>(d);
        d += swz<SWZ_X8>(d);
        sc[ch] = ((mbits >> ch) & 1) ? d * 5.0f : -1e6f;
    }

    // Running max over 32 (8 regs x 4 r-groups).
    float mx = sc[0];
    #pragma unroll
    for (int ch = 1; ch < 8; ch++) mx = fmaxf(mx, sc[ch]);
    mx = fmaxf(mx, swz<SWZ_X16>(mx));
    mx = fmaxf(mx, __shfl_xor(mx, 32));

    // Unnormalized probs. Masked: exp(-1e6 - mx) == +0.0f. All-masked s:
    // exp(0) == 1 > PTHR for every ch, so the filter below loads the TRUE
    // neighbor rows and inv == rcp(32) (exact) gives the uniform mean.
    float p[8];
    float sum = 0.f;
    #pragma unroll
    for (int ch = 0; ch < 8; ch++) {
        p[ch] = __expf(sc[ch] - mx);
        sum += p[ch];
    }

    // Phase 2: agg gathers, issued BEFORE the softmax tail so the sum
    // butterfly + rcp hide their latency. Fetch filter: p <= PTHR rows
    // (masked, underflowed, or negligible) redirect to the q line -- zero
    // new cache lines; their contribution is dropped (error <= 5e-6).
    f16x8 vv[8];
    #pragma unroll
    for (int ch = 0; ch < 8; ch++) {
        const unsigned o = (p[ch] > PTHR) ? (((unsigned)nbv[ch] << 9) + cb + 256)
                                          : qoff;
        vv[ch] = *(const f16x8*)(Tb + o);
    }
    __builtin_amdgcn_sched_barrier(0);   // all 8 vv airborne before agg/tail

    sum += swz<SWZ_X16>(sum);
    sum += __shfl_xor(sum, 32);
    const float inv = __builtin_amdgcn_rcpf(sum);

    // Agg with UNNORMALIZED p; single scale by inv after the final butterfly.
    // Filtered channels must not touch acc (their vv is the q line): zero p.
    float acc[8] = {0.f, 0.f, 0.f, 0.f, 0.f, 0.f, 0.f, 0.f};
    #pragma unroll
    for (int ch = 0; ch < 8; ch++) {
        const float pc = (p[ch] > PTHR) ? p[ch] : 0.f;
        #pragma unroll
        for (int j = 0; j < 8; j++)
            acc[j] += pc * (float)vv[ch][j];
    }

    // Cross-group butterfly: sum the 4 r-group partials, then normalize.
    #pragma unroll
    for (int j = 0; j < 8; j++) {
        acc[j] += swz<SWZ_X16>(acc[j]);
        acc[j] += __shfl_xor(acc[j], 32);
        acc[j] *= inv;
    }

    // lane (r,c) writes cols c*8 + r*2 + {0,1}: contiguous 512 B per wave.
    *((float2*)(out + (size_t)src * CC) + c * 4 + r) =
        make_float2(acc[r * 2], acc[r * 2 + 1]);
}

extern "C" void kernel_launch(void* const* d_in, const int* in_sizes, int n_in,
                              void* d_out, int out_size, void* d_ws, size_t ws_size,
                              hipStream_t stream)
{
    const float* wv   = (const float*)d_in[0];
    const int*   src  = (const int*)d_in[1];
    const int*   nei  = (const int*)d_in[2];
    const int*   msk  = (const int*)d_in[3];
    const float* W    = (const float*)d_in[4];
    const float* bias = (const float*)d_in[5];
    float* out = (float*)d_out;
    _Float16* T = (_Float16*)d_ws;   // 100000 * 512 B = 51.2 MB

    proj_kernel<<<NN / RPB, 256, 0, stream>>>(wv, W, bias, T, out);           // 1250
    attn_kernel<<<(SS * 64) / 256, 256, 0, stream>>>(T, src, nei, msk, out);  // 12500
}

// Round 8
// 171.715 us; speedup vs baseline: 1.0322x; 1.0322x over previous
//
#include <hip/hip_runtime.h>

#define NN 100000
#define SS 50000
#define KK 32
#define CC 128
#define RPB 160          // rows per proj block; 625 * 160 = 100000
                         // (R8: reverted to 160 -- RPB 80 doubled per-block
                         // W staging traffic (40->80 MB) and cost ~3 us)
#define LDA 136          // LDS row stride in halfs (272 B = 17*16, b128-aligned)
#define PTHR 1e-8f       // agg fetch filter: p_raw below this contributes
                         // <= 32*1e-8*|v|max ~ 5e-6 after normalization

typedef _Float16 f16x8 __attribute__((ext_vector_type(8)));
typedef _Float16 f16x4 __attribute__((ext_vector_type(4)));
typedef _Float16 f16x2 __attribute__((ext_vector_type(2)));
typedef float f32x4 __attribute__((ext_vector_type(4)));

// Butterfly-sum steps as DPP: the lane exchange rides the VALU add as a
// source modifier -- no DS-pipe op, no address math, 1 instruction/step.
// Valid because every wave is fully active (grid maps waves 1:1 to s).
//   0xB1  = quad_perm(1,0,3,2)  -> xor1
//   0x4E  = quad_perm(2,3,0,1)  -> xor2
//   0x141 = ROW_HALF_MIRROR     -> 8-group exchange (quad-uniform by then)
//   0x140 = ROW_MIRROR          -> 16-group exchange (8-uniform by then)
template<int CTRL>
__device__ __forceinline__ float dpp_add(float x) {
    const int m = __builtin_amdgcn_update_dpp(0, __float_as_int(x),
                                              CTRL, 0xF, 0xF, true);
    return x + __int_as_float(m);
}

// xor16 lane exchange: single-instruction ds_swizzle BitMode
// (offset = (xor<<10) | 0x1F). Not DPP-expressible (crosses 16-lane rows).
#define SWZ_X16 0x401F
__device__ __forceinline__ float swz16(float x) {
    return __int_as_float(__builtin_amdgcn_ds_swizzle(__float_as_int(x), SWZ_X16));
}

// Workspace table T: per row i (512 B stride, 256 halfs):
//   T[i*256 +   0 .. 127] = fp16(word_vec[i])   (proj staging loop)
//   T[i*256 + 128 .. 255] = fp16(P[i])          (proj epilogue)

// ---------------------------------------------------------------------------
// Kernel 1 (fused convert+proj): P = leaky_relu(wv @ W^T + b) via
// mfma_f32_16x16x32_f16. 160 rows/block staged once into LDS (fp16, padded)
// with coalesced float4 loads; same loop publishes the fp16 wv copy to T.
// A-frags from LDS (broadcast); B-frags register-resident per wave.
// Exact R6 proj (best measured).
// ---------------------------------------------------------------------------
__global__ __launch_bounds__(256) void proj_kernel(
    const float* __restrict__ wv,
    const float* __restrict__ W,
    const float* __restrict__ bias,
    _Float16* __restrict__ T,
    float* __restrict__ out)
{
    __shared__ _Float16 sA[RPB][LDA];

    const int t = threadIdx.x;
    const int base = blockIdx.x * RPB;

    // Stage A (160 x 128 fp32 -> fp16 LDS + T copy). 20 float4 per thread.
    #pragma unroll 4
    for (int i = 0; i < 20; i++) {
        const int idx = i * 256 + t;
        const int row = idx >> 5;
        const int c4 = (idx & 31) * 4;
        const float4 v = *(const float4*)(wv + (size_t)(base + row) * CC + c4);
        f16x4 h;
        h[0] = (_Float16)v.x; h[1] = (_Float16)v.y;
        h[2] = (_Float16)v.z; h[3] = (_Float16)v.w;
        *(f16x4*)&sA[row][c4] = h;
        *(f16x4*)(T + (size_t)(base + row) * 256 + c4) = h;
    }

    const int w = t >> 6;
    const int l = t & 63;
    const int q = l >> 4;      // quad 0..3
    const int c = l & 15;

    // B-frags: B[k][n] = W[n][k]; lane holds n = w*32+nch*16+c, k = kc*32+q*8+j
    f16x8 bf[2][4];
    float bo[2];
    #pragma unroll
    for (int nch = 0; nch < 2; nch++) {
        const int n = w * 32 + nch * 16 + c;
        bo[nch] = bias[n];
        const float* Wr = W + (size_t)n * CC;
        #pragma unroll
        for (int kc = 0; kc < 4; kc++) {
            const int k0 = kc * 32 + q * 8;
            const float4 w0 = *(const float4*)(Wr + k0);
            const float4 w1 = *(const float4*)(Wr + k0 + 4);
            f16x8 b;
            b[0] = (_Float16)w0.x; b[1] = (_Float16)w0.y;
            b[2] = (_Float16)w0.z; b[3] = (_Float16)w0.w;
            b[4] = (_Float16)w1.x; b[5] = (_Float16)w1.y;
            b[6] = (_Float16)w1.z; b[7] = (_Float16)w1.w;
            bf[nch][kc] = b;
        }
    }
    __syncthreads();

    #pragma unroll 2
    for (int sub = 0; sub < RPB / 16; sub++) {
        const int rl = sub * 16 + c;

        f16x8 af[4];
        #pragma unroll
        for (int kc = 0; kc < 4; kc++)
            af[kc] = *(const f16x8*)&sA[rl][kc * 32 + q * 8];

        f32x4 acc[2] = {{0.f, 0.f, 0.f, 0.f}, {0.f, 0.f, 0.f, 0.f}};
        #pragma unroll
        for (int kc = 0; kc < 4; kc++) {
            acc[0] = __builtin_amdgcn_mfma_f32_16x16x32_f16(af[kc], bf[0][kc], acc[0], 0, 0, 0);
            acc[1] = __builtin_amdgcn_mfma_f32_16x16x32_f16(af[kc], bf[1][kc], acc[1], 0, 0, 0);
        }

        // D layout: col = c (+tile offset), row = q*4 + reg.
        #pragma unroll
        for (int nch = 0; nch < 2; nch++) {
            const int col = w * 32 + nch * 16 + c;
            #pragma unroll
            for (int r = 0; r < 4; r++) {
                const int row = base + sub * 16 + q * 4 + r;
                float v = acc[nch][r] + bo[nch];
                v = v > 0.f ? v : 0.2f * v;
                out[(size_t)row * CC + col] = v;
                T[(size_t)row * 256 + 128 + col] = (_Float16)v;
            }
        }
    }
}

// ---------------------------------------------------------------------------
// Kernel 2: one wave per s, lane = r*16+c. R6 structure kept (p-based vv
// fetch filter at PTHR=1e-8, vv issue under the softmax tail, grouped gather
// issue, batched index prologue). R8: the score-reduce butterfly (xor1/2/4/8,
// 32 exchanges + 32 adds -- the hottest serial chain) becomes 32 DPP-adds:
// cross-lane movement fused into the VALU add, zero DS-pipe ops, chain step
// cost drops from DS-latency+add to one VALU slot. xor16 stays ds_swizzle,
// xor32 stays shfl (not DPP-expressible).
// ---------------------------------------------------------------------------
__global__ __launch_bounds__(256, 8) void attn_kernel(
    const _Float16* __restrict__ T,
    const int* __restrict__ src_idx,
    const int* __restrict__ neighs,
    const int* __restrict__ mask,
    float* __restrict__ out)
{
    const int s = (blockIdx.x * 256 + threadIdx.x) >> 6;
    if (s >= SS) return;
    const int lane = threadIdx.x & 63;
    const int c = lane & 15;
    const int r = lane >> 4;

    // Batched index load: lane l (and l+32) holds element l&31 of the row.
    const int e = lane & 31;
    const int nb_l = neighs[s * KK + e];
    const int mk_l = mask[s * KK + e];
    const int src = src_idx[s];

    const unsigned long long mb = __ballot(mk_l == 1);   // bit l = mask[l&31]

    int nbv[8], mbits = 0;
    #pragma unroll
    for (int ch = 0; ch < 8; ch++) {
        nbv[ch] = __shfl(nb_l, ch * 4 + r);
        mbits |= (int)((mb >> (ch * 4 + r)) & 1ull) << ch;
    }

    const char* Tb = (const char*)T;
    const unsigned cb = (unsigned)c << 4;
    const unsigned qoff = ((unsigned)src << 9) + cb;   // q line: L1-hot anchor

    // Phase 1: score gathers, grouped issue. Masked rows -> q line (no new
    // cache lines; values arithmetically discarded).
    const f16x8 qh = *(const f16x8*)(Tb + qoff);
    f16x8 kh[8];
    #pragma unroll
    for (int ch = 0; ch < 8; ch++) {
        const unsigned o = ((mbits >> ch) & 1) ? (((unsigned)nbv[ch] << 9) + cb)
                                               : qoff;
        kh[ch] = *(const f16x8*)(Tb + o);
    }
    __builtin_amdgcn_sched_barrier(0);   // all 8 kh airborne before the dots

    float sc[8];
    #pragma unroll
    for (int ch = 0; ch < 8; ch++) {
        float d = 0.f;
        #pragma unroll
        for (int j = 0; j < 4; j++) {
            f16x2 qa; qa[0] = qh[2 * j];     qa[1] = qh[2 * j + 1];
            f16x2 ka; ka[0] = kh[ch][2 * j]; ka[1] = kh[ch][2 * j + 1];
            d = __builtin_amdgcn_fdot2(qa, ka, d, false);
        }
        // 16-lane butterfly sum, all-DPP (see helper comments).
        d = dpp_add<0xB1>(d);    // xor1
        d = dpp_add<0x4E>(d);    // xor2
        d = dpp_add<0x141>(d);   // 8-group exchange
        d = dpp_add<0x140>(d);   // 16-group exchange
        sc[ch] = ((mbits >> ch) & 1) ? d * 5.0f : -1e6f;
    }

    // Running max over 32 (8 regs x 4 r-groups).
    float mx = sc[0];
    #pragma unroll
    for (int ch = 1; ch < 8; ch++) mx = fmaxf(mx, sc[ch]);
    mx = fmaxf(mx, swz16(mx));
    mx = fmaxf(mx, __shfl_xor(mx, 32));

    // Unnormalized probs. Masked: exp(-1e6 - mx) == +0.0f. All-masked s:
    // exp(0) == 1 > PTHR for every ch, so the filter below loads the TRUE
    // neighbor rows and inv == rcp(32) (exact) gives the uniform mean.
    float p[8];
    float sum = 0.f;
    #pragma unroll
    for (int ch = 0; ch < 8; ch++) {
        p[ch] = __expf(sc[ch] - mx);
        sum += p[ch];
    }

    // Phase 2: agg gathers, issued BEFORE the softmax tail so the sum
    // butterfly + rcp hide their latency. Fetch filter: p <= PTHR rows
    // (masked, underflowed, or negligible) redirect to the q line -- zero
    // new cache lines; their contribution is dropped (error <= 5e-6).
    f16x8 vv[8];
    #pragma unroll
    for (int ch = 0; ch < 8; ch++) {
        const unsigned o = (p[ch] > PTHR) ? (((unsigned)nbv[ch] << 9) + cb + 256)
                                          : qoff;
        vv[ch] = *(const f16x8*)(Tb + o);
    }
    __builtin_amdgcn_sched_barrier(0);   // all 8 vv airborne before agg/tail

    sum += swz16(sum);
    sum += __shfl_xor(sum, 32);
    const float inv = __builtin_amdgcn_rcpf(sum);

    // Agg with UNNORMALIZED p; single scale by inv after the final butterfly.
    // Filtered channels must not touch acc (their vv is the q line): zero p.
    float acc[8] = {0.f, 0.f, 0.f, 0.f, 0.f, 0.f, 0.f, 0.f};
    #pragma unroll
    for (int ch = 0; ch < 8; ch++) {
        const float pc = (p[ch] > PTHR) ? p[ch] : 0.f;
        #pragma unroll
        for (int j = 0; j < 8; j++)
            acc[j] += pc * (float)vv[ch][j];
    }

    // Cross-group butterfly: sum the 4 r-group partials, then normalize.
    #pragma unroll
    for (int j = 0; j < 8; j++) {
        acc[j] += swz16(acc[j]);
        acc[j] += __shfl_xor(acc[j], 32);
        acc[j] *= inv;
    }

    // lane (r,c) writes cols c*8 + r*2 + {0,1}: contiguous 512 B per wave.
    *((float2*)(out + (size_t)src * CC) + c * 4 + r) =
        make_float2(acc[r * 2], acc[r * 2 + 1]);
}

extern "C" void kernel_launch(void* const* d_in, const int* in_sizes, int n_in,
                              void* d_out, int out_size, void* d_ws, size_t ws_size,
                              hipStream_t stream)
{
    const float* wv   = (const float*)d_in[0];
    const int*   src  = (const int*)d_in[1];
    const int*   nei  = (const int*)d_in[2];
    const int*   msk  = (const int*)d_in[3];
    const float* W    = (const float*)d_in[4];
    const float* bias = (const float*)d_in[5];
    float* out = (float*)d_out;
    _Float16* T = (_Float16*)d_ws;   // 100000 * 512 B = 51.2 MB

    proj_kernel<<<NN / RPB, 256, 0, stream>>>(wv, W, bias, T, out);           // 625
    attn_kernel<<<(SS * 64) / 256, 256, 0, stream>>>(T, src, nei, msk, out);  // 12500
}